// Round 3
// baseline (420.119 us; speedup 1.0000x reference)
//
#include <hip/hip_runtime.h>
#include <stdint.h>

// ---------------------------------------------------------------------------
// PatchEmbed + HMQConv2d fake-quant, fp32 I/O.
//   s_x = max(max|x|,1e-8)/127 ; s_w = max(max|w|,1e-8)/127
//   out[b, gx*28+gy, d] = (sum_k qx*qw) * s_x*s_w + bias[d]
// GEMM M=50176, N=768, K=192, int8 codes, mfma_i32_16x16x64_i8 (exact).
//
// Round-8: absmax+quant fused into ONE kernel (x read from HBM exactly once).
// Each block holds its 21.5KB x-slice in registers across a device-wide
// atomic barrier (atomicMax on |x| bits + release counter), then quantizes
// from registers. Safety: 1828 blocks * 4 waves = 7312 <= 8192 wave capacity
// with __launch_bounds__(256,8) (VGPR<=64, LDS 5.9KB) -> ALL blocks
// co-resident regardless of dispatch order -> spin barrier cannot starve.
// W path uses its own 36-block mini-barrier. init_k zeroes the 4 sync words
// (ws is re-poisoned every iteration; no init-free protocol is safe).
// R7 post-mortem: gain (-32us) was 3x the traffic model -> GEMM had been
// load-issue bound, now near its 154MB-write floor. Remaining reducible:
// x double-read (6.5us) + one launch bubble. Predict 200 -> ~191.
// ---------------------------------------------------------------------------

using f32x4 = __attribute__((ext_vector_type(4))) float;
using i32x4 = __attribute__((ext_vector_type(4))) int;

static __device__ __forceinline__ uint32_t q4i8(float4 v, float inv_s) {
  int q0 = (int)rintf(fminf(fmaxf(v.x * inv_s, -127.0f), 127.0f));
  int q1 = (int)rintf(fminf(fmaxf(v.y * inv_s, -127.0f), 127.0f));
  int q2 = (int)rintf(fminf(fmaxf(v.z * inv_s, -127.0f), 127.0f));
  int q3 = (int)rintf(fminf(fmaxf(v.w * inv_s, -127.0f), 127.0f));
  return (uint32_t)(q0 & 0xff) | ((uint32_t)(q1 & 0xff) << 8) |
         ((uint32_t)(q2 & 0xff) << 16) | ((uint32_t)(q3 & 0xff) << 24);
}

#define NXB 1792   // x blocks: one per (b,gx)
#define NWB 36     // w blocks

// sync[0]=absmax_x bits, sync[1]=ctr_x, sync[2]=absmax_w bits, sync[3]=ctr_w
__global__ void init_k(uint32_t* __restrict__ sync) {
  if (threadIdx.x < 4) sync[threadIdx.x] = 0;
}

__global__ __launch_bounds__(256, 8) void prep_k(
    const float* __restrict__ x, const float4* __restrict__ w4,
    uint4* __restrict__ Aq, uint4* __restrict__ Wq,
    uint32_t* __restrict__ sync, float* __restrict__ slots) {
  __shared__ float red[4];
  __shared__ float s_scale;
  __shared__ uint2 stg8[28][26];   // [gy][octet], row padded 24->26
  const int tid = threadIdx.x;
  const int bid = blockIdx.x;

  if (bid < NXB) {
    const int b  = bid / 28;
    const int gx = bid - b * 28;
    // 672 octet tasks: r = c*8+p (x row / k-octet), gy = patch col.
    // Thread holds tasks {tid, tid+256, tid+512(<672)} in registers.
    float4 A0[3], A1[3];
    float mx = 0.0f;
#pragma unroll
    for (int s = 0; s < 3; ++s) {
      if (s < 2 || tid < 160) {
        const int t  = tid + s * 256;
        const int r  = t / 28;
        const int gy = t - r * 28;
        const int c = r >> 3, p = r & 7;
        const float4* src =
            (const float4*)(x + (size_t)((b * 3 + c) * 224 + gx * 8 + p) * 224);
        A0[s] = src[gy * 2];
        A1[s] = src[gy * 2 + 1];
        mx = fmaxf(mx, fmaxf(fmaxf(fabsf(A0[s].x), fabsf(A0[s].y)),
                             fmaxf(fabsf(A0[s].z), fabsf(A0[s].w))));
        mx = fmaxf(mx, fmaxf(fmaxf(fabsf(A1[s].x), fabsf(A1[s].y)),
                             fmaxf(fabsf(A1[s].z), fabsf(A1[s].w))));
      }
    }
#pragma unroll
    for (int off = 32; off > 0; off >>= 1) mx = fmaxf(mx, __shfl_down(mx, off, 64));
    if ((tid & 63) == 0) red[tid >> 6] = mx;
    __syncthreads();
    if (tid == 0) {
      float m = fmaxf(fmaxf(red[0], red[1]), fmaxf(red[2], red[3]));
      __hip_atomic_fetch_max(&sync[0], __float_as_uint(m),
                             __ATOMIC_RELAXED, __HIP_MEMORY_SCOPE_AGENT);
      __hip_atomic_fetch_add(&sync[1], 1u,
                             __ATOMIC_RELEASE, __HIP_MEMORY_SCOPE_AGENT);
      while (__hip_atomic_load(&sync[1], __ATOMIC_ACQUIRE,
                               __HIP_MEMORY_SCOPE_AGENT) < NXB)
        __builtin_amdgcn_s_sleep(2);
      uint32_t mb = __hip_atomic_load(&sync[0], __ATOMIC_RELAXED,
                                      __HIP_MEMORY_SCOPE_AGENT);
      s_scale = fmaxf(__uint_as_float(mb), 1e-8f) * (1.0f / 127.0f);
    }
    __syncthreads();
    const float sxs = s_scale;
    if (bid == 0 && tid == 0) slots[0] = sxs;   // for gemm epilogue

    // quantize from registers -> LDS transpose staging
    const float inv = 1.0f / sxs;
#pragma unroll
    for (int s = 0; s < 3; ++s) {
      if (s < 2 || tid < 160) {
        const int t  = tid + s * 256;
        const int r  = t / 28;
        const int gy = t - r * 28;
        uint2 q;
        q.x = q4i8(A0[s], inv);
        q.y = q4i8(A1[s], inv);
        stg8[gy][r] = q;
      }
    }
    __syncthreads();
    // contiguous stream-out: rows m = b*784+gx*28 + [0,28), 28*12 uint4
    uint4* dst = Aq + (size_t)(b * 784 + gx * 28) * 12;
    for (int t = tid; t < 336; t += 256) {
      const int gy = t / 12;
      const int j  = t - gy * 12;
      uint2 lo = stg8[gy][2 * j], hi = stg8[gy][2 * j + 1];
      uint4 v; v.x = lo.x; v.y = lo.y; v.z = hi.x; v.w = hi.y;
      dst[t] = v;
    }
  } else {
    // ---- w: 36 blocks, 16 floats/thread in regs, own mini-barrier ----
    const int g = (bid - NXB) * 256 + tid;           // < 9,216
    float4 B0 = w4[g * 4], B1 = w4[g * 4 + 1];
    float4 B2 = w4[g * 4 + 2], B3 = w4[g * 4 + 3];
    float mw = 0.0f;
    mw = fmaxf(mw, fmaxf(fmaxf(fabsf(B0.x), fabsf(B0.y)), fmaxf(fabsf(B0.z), fabsf(B0.w))));
    mw = fmaxf(mw, fmaxf(fmaxf(fabsf(B1.x), fabsf(B1.y)), fmaxf(fabsf(B1.z), fabsf(B1.w))));
    mw = fmaxf(mw, fmaxf(fmaxf(fabsf(B2.x), fabsf(B2.y)), fmaxf(fabsf(B2.z), fabsf(B2.w))));
    mw = fmaxf(mw, fmaxf(fmaxf(fabsf(B3.x), fabsf(B3.y)), fmaxf(fabsf(B3.z), fabsf(B3.w))));
#pragma unroll
    for (int off = 32; off > 0; off >>= 1) mw = fmaxf(mw, __shfl_down(mw, off, 64));
    if ((tid & 63) == 0) red[tid >> 6] = mw;
    __syncthreads();
    if (tid == 0) {
      float m = fmaxf(fmaxf(red[0], red[1]), fmaxf(red[2], red[3]));
      __hip_atomic_fetch_max(&sync[2], __float_as_uint(m),
                             __ATOMIC_RELAXED, __HIP_MEMORY_SCOPE_AGENT);
      __hip_atomic_fetch_add(&sync[3], 1u,
                             __ATOMIC_RELEASE, __HIP_MEMORY_SCOPE_AGENT);
      while (__hip_atomic_load(&sync[3], __ATOMIC_ACQUIRE,
                               __HIP_MEMORY_SCOPE_AGENT) < NWB)
        __builtin_amdgcn_s_sleep(2);
      uint32_t mb = __hip_atomic_load(&sync[2], __ATOMIC_RELAXED,
                                      __HIP_MEMORY_SCOPE_AGENT);
      s_scale = fmaxf(__uint_as_float(mb), 1e-8f) * (1.0f / 127.0f);
    }
    __syncthreads();
    const float sws = s_scale;
    if (bid == NXB && tid == 0) slots[1] = sws;

    const float inv = 1.0f / sws;
    uint4 q;
    q.x = q4i8(B0, inv); q.y = q4i8(B1, inv);
    q.z = q4i8(B2, inv); q.w = q4i8(B3, inv);
    Wq[g] = q;                                       // flat order == [d][k]
  }
}

// ---------------------------------------------------------------------------
// Pure int8 code-GEMM, mfma_i32_16x16x64_i8 (K=192 = 3 steps). Unchanged R7.
//   A frag: A[m = lane&15][k = (lane>>4)*16 + j] -> uint4 @ m*12 + lq + ks*4
//   B frag: W[n = lane&15][k = (lane>>4)*16 + j] -> uint4 @ n*12 + lq + ks*4
//   D:      row = (lane>>4)*4 + reg, col = lane&15
// ---------------------------------------------------------------------------
__global__ __launch_bounds__(256) void gemm_k(
    const uint4* __restrict__ Aq, const uint4* __restrict__ Wq,
    const float* __restrict__ bias, const float* __restrict__ slots,
    float* __restrict__ out) {
  __shared__ float tr[4 * 1280];       // per wave: 64 cols x 20 (16 rows+pad)
  const int tid  = threadIdx.x;
  const int lane = tid & 63;
  const int wid  = tid >> 6;
  const int wm   = wid >> 1;   // 0..1
  const int wn   = wid & 1;    // 0..1
  const int lm   = lane & 15;
  const int lq   = lane >> 4;  // 0..3
  const int m0   = blockIdx.x * 128;   // 392 m-tiles (392%8==0 -> XCD-local)
  const int n0   = blockIdx.y * 128;   // 6 n-tiles

  int abase[4], bbase[4];
#pragma unroll
  for (int tm = 0; tm < 4; ++tm)
    abase[tm] = (m0 + wm * 64 + tm * 16 + lm) * 12 + lq;
#pragma unroll
  for (int tn = 0; tn < 4; ++tn)
    bbase[tn] = (n0 + wn * 64 + tn * 16 + lm) * 12 + lq;

  i32x4 acc[4][4] = {};

#pragma unroll
  for (int ks = 0; ks < 3; ++ks) {     // K=64 per step
    i32x4 af[4], bf[4];
#pragma unroll
    for (int tm = 0; tm < 4; ++tm)
      af[tm] = __builtin_bit_cast(i32x4, Aq[abase[tm] + ks * 4]);
#pragma unroll
    for (int tn = 0; tn < 4; ++tn)
      bf[tn] = __builtin_bit_cast(i32x4, Wq[bbase[tn] + ks * 4]);
#pragma unroll
    for (int tm = 0; tm < 4; ++tm)
#pragma unroll
      for (int tn = 0; tn < 4; ++tn)
        acc[tm][tn] = __builtin_amdgcn_mfma_i32_16x16x64_i8(
            af[tm], bf[tn], acc[tm][tn], 0, 0, 0);
  }

  // ---- epilogue: i32->f32, wave-local transpose, float4 stores ----
  const float scale = slots[0] * slots[1];
  float* T = &tr[wid * 1280];
  const int c4 = lane & 15;                       // float4-column group
  const int gc = n0 + wn * 64 + c4 * 4;
  const float4 bv = *(const float4*)&bias[gc];    // hoisted: c4 fixed per lane

#pragma unroll
  for (int tm = 0; tm < 4; ++tm) {
#pragma unroll
    for (int tn = 0; tn < 4; ++tn) { // element (row=lq*4+j, col=tn*16+lm)
      f32x4 f;
#pragma unroll
      for (int j = 0; j < 4; ++j) f[j] = (float)acc[tm][tn][j];
      *(f32x4*)&T[(tn * 16 + lm) * 20 + lq * 4] = f;
    }
    asm volatile("s_waitcnt lgkmcnt(0)" ::: "memory");
#pragma unroll
    for (int i = 0; i < 4; ++i) {
      const int s = (lane >> 4) + i * 4;          // row 0..15 of this stripe
      float4 v;
      v.x = T[(c4 * 4 + 0) * 20 + s];
      v.y = T[(c4 * 4 + 1) * 20 + s];
      v.z = T[(c4 * 4 + 2) * 20 + s];
      v.w = T[(c4 * 4 + 3) * 20 + s];
      float4 o;
      o.x = fmaf(v.x, scale, bv.x);
      o.y = fmaf(v.y, scale, bv.y);
      o.z = fmaf(v.z, scale, bv.z);
      o.w = fmaf(v.w, scale, bv.w);
      const int gm = m0 + wm * 64 + tm * 16 + s;
      *(float4*)&out[(size_t)gm * 768 + gc] = o;
    }
    asm volatile("s_waitcnt lgkmcnt(0)" ::: "memory");  // drain reads before next tm rewrites T
  }
}

// ---------------------------------------------------------------------------

extern "C" void kernel_launch(void* const* d_in, const int* in_sizes, int n_in,
                              void* d_out, int out_size, void* d_ws, size_t ws_size,
                              hipStream_t stream) {
  const float* xf = (const float*)d_in[0];       // 9,633,792 fp32
  const float4* w4 = (const float4*)d_in[1];     //   147,456 fp32
  const float* bias = (const float*)d_in[2];     //       768 fp32
  float* out = (float*)d_out;                    // 38,535,168 fp32

  char* ws = (char*)d_ws;
  float* slots    = (float*)ws;                  // [0]=s_x, [1]=s_w
  uint32_t* sync  = (uint32_t*)(ws + 64);        // 4 words, init_k-zeroed
  uint4* Wq       = (uint4*)(ws + 8192);         //   147,456 B int8 codes
  uint4* Aq       = (uint4*)(ws + 8192 + 147456);// 9,633,792 B int8 codes

  init_k<<<1, 64, 0, stream>>>(sync);
  prep_k<<<NXB + NWB, 256, 0, stream>>>(xf, w4, Aq, Wq, sync, slots);
  gemm_k<<<dim3(392, 6), 256, 0, stream>>>(Aq, Wq, bias, slots, out);
}

// Round 5
// 207.954 us; speedup vs baseline: 2.0203x; 2.0203x over previous
//
#include <hip/hip_runtime.h>
#include <stdint.h>

// ---------------------------------------------------------------------------
// PatchEmbed + HMQConv2d fake-quant, fp32 I/O.
//   s_x = max(max|x|,1e-8)/127 ; s_w = max(max|w|,1e-8)/127
//   out[b, gx*28+gy, d] = (sum_k qx*qw) * s_x*s_w + bias[d]
// GEMM M=50176, N=768, K=192, int8 codes, mfma_i32_16x16x64_i8 (exact:
// |acc| <= 192*127^2 << 2^31).
//
// Round-9 (recompile: nontemporal builtin needs native ext_vector, not HIP
// float4). REVERT of round-8's fused device-barrier kernel (420us: AGENT-
// scope spin barrier cost ~250us of idle — cross-XCD coherence makes
// release/acquire on one hot line catastrophically serial on MI355X.
// Lesson: never hand-roll device-wide barriers here; a 3us L3-hot re-read
// of x is far cheaper). Back to the R7 3-kernel chain (200.3us) plus:
//  (a) absmax re-tiled to the SAME (b,gx) block decomposition as quant:
//      with consistent bid->XCD round-robin, quant re-reads its slice from
//      the local XCD L2 (38MB -> ~4.8MB/XCD) instead of L3/HBM.
//  (b) gemm output stores non-temporal: out is never re-read; keep the
//      154MB stream out of L2 so Aq stays resident for the 6 column tiles.
// Kernel chain is ~40us vs ~38us traffic floor; the remaining ~155us of
// the timed quantum is harness re-poison fills (602MB @ ~6.8TB/s each).
// ---------------------------------------------------------------------------

using f32x4 = __attribute__((ext_vector_type(4))) float;
using i32x4 = __attribute__((ext_vector_type(4))) int;

static __device__ __forceinline__ uint32_t q4i8(float4 v, float inv_s) {
  // 4 floats -> 4 int8 codes packed LE (byte 0 = v.x)
  int q0 = (int)rintf(fminf(fmaxf(v.x * inv_s, -127.0f), 127.0f));
  int q1 = (int)rintf(fminf(fmaxf(v.y * inv_s, -127.0f), 127.0f));
  int q2 = (int)rintf(fminf(fmaxf(v.z * inv_s, -127.0f), 127.0f));
  int q3 = (int)rintf(fminf(fmaxf(v.w * inv_s, -127.0f), 127.0f));
  return (uint32_t)(q0 & 0xff) | ((uint32_t)(q1 & 0xff) << 8) |
         ((uint32_t)(q2 & 0xff) << 16) | ((uint32_t)(q3 & 0xff) << 24);
}

#define NAXB 1792   // absmax/quant x blocks: one per (b,gx)
#define NAWB 36     // w blocks: 256 thr * 16 floats = 4096 floats each

// ---- absmax: same tiling as quant so quant's re-read is XCD-L2-local ------
__global__ __launch_bounds__(256) void absmax_k(
    const float* __restrict__ x, const float4* __restrict__ w4,
    float* __restrict__ partials) {
  __shared__ float red[4];
  const int tid = threadIdx.x;
  const int bid = blockIdx.x;
  float m = 0.0f;
  if (bid < NAXB) {
    const int b  = bid / 28;
    const int gx = bid - b * 28;
    for (int t = tid; t < 672; t += 256) {
      const int r  = t / 28;            // 0..23 = c*8+p (x row)
      const int gy = t - r * 28;        // 0..27
      const int c = r >> 3, p = r & 7;
      const float4* src =
          (const float4*)(x + (size_t)((b * 3 + c) * 224 + gx * 8 + p) * 224);
      float4 a0 = src[gy * 2], a1 = src[gy * 2 + 1];
      m = fmaxf(m, fmaxf(fmaxf(fabsf(a0.x), fabsf(a0.y)),
                         fmaxf(fabsf(a0.z), fabsf(a0.w))));
      m = fmaxf(m, fmaxf(fmaxf(fabsf(a1.x), fabsf(a1.y)),
                         fmaxf(fabsf(a1.z), fabsf(a1.w))));
    }
  } else {
    const int g = (bid - NAXB) * 256 + tid;   // < 9,216
    float4 b0 = w4[g * 4], b1 = w4[g * 4 + 1];
    float4 b2 = w4[g * 4 + 2], b3 = w4[g * 4 + 3];
    m = fmaxf(m, fmaxf(fmaxf(fabsf(b0.x), fabsf(b0.y)), fmaxf(fabsf(b0.z), fabsf(b0.w))));
    m = fmaxf(m, fmaxf(fmaxf(fabsf(b1.x), fabsf(b1.y)), fmaxf(fabsf(b1.z), fabsf(b1.w))));
    m = fmaxf(m, fmaxf(fmaxf(fabsf(b2.x), fabsf(b2.y)), fmaxf(fabsf(b2.z), fabsf(b2.w))));
    m = fmaxf(m, fmaxf(fmaxf(fabsf(b3.x), fabsf(b3.y)), fmaxf(fabsf(b3.z), fabsf(b3.w))));
  }
#pragma unroll
  for (int off = 32; off > 0; off >>= 1) m = fmaxf(m, __shfl_down(m, off, 64));
  if ((tid & 63) == 0) red[tid >> 6] = m;
  __syncthreads();
  if (tid == 0)
    partials[bid] = fmaxf(fmaxf(red[0], red[1]), fmaxf(red[2], red[3]));
}

// ---- quant both ------------------------------------------------------------
// x blocks [0,1792): block = (b,gx), SAME slice absmax block bid just read
// (XCD-L2-hot). Stage 28 Aq rows (192 int8 each) through LDS: x reads
// coalesced, Aq written as one contiguous 5376B stream per block.
// w blocks [1792,1828): 16 floats/thread, flat [d][k] uint4 stores.
// Prologue (all blocks): reduce 1828 absmax partials (L2-hot, ~free);
// block 0 publishes slots for the gemm epilogue.
__global__ __launch_bounds__(256) void quant_xw_k(
    const float* __restrict__ x, const float4* __restrict__ w4,
    uint4* __restrict__ Aq, uint4* __restrict__ Wq,
    const float* __restrict__ partials, float* __restrict__ slots) {
  __shared__ float redx[4];
  __shared__ float redw_s;
  __shared__ uint2 stg8[28][26];   // [gy][octet], row padded 24->26 uint2
  const int tid = threadIdx.x;

  // ---- scales (every block) ----
  float mx = 0.0f;
  for (int i = tid; i < NAXB; i += 256) mx = fmaxf(mx, partials[i]);  // 7 each
#pragma unroll
  for (int off = 32; off > 0; off >>= 1) mx = fmaxf(mx, __shfl_down(mx, off, 64));
  if ((tid & 63) == 0) redx[tid >> 6] = mx;
  if (tid < 64) {
    float mw = (tid < NAWB) ? partials[NAXB + tid] : 0.0f;
#pragma unroll
    for (int off = 32; off > 0; off >>= 1) mw = fmaxf(mw, __shfl_down(mw, off, 64));
    if (tid == 0) redw_s = mw;
  }
  __syncthreads();
  float sx = fmaxf(fmaxf(redx[0], redx[1]), fmaxf(redx[2], redx[3]));
  sx = fmaxf(sx, 1e-8f) * (1.0f / 127.0f);
  float sw = fmaxf(redw_s, 1e-8f) * (1.0f / 127.0f);
  if (blockIdx.x == 0 && tid == 0) { slots[0] = sx; slots[1] = sw; }

  if (blockIdx.x < NAXB) {
    const float inv = 1.0f / sx;
    const int b  = blockIdx.x / 28;
    const int gx = blockIdx.x - b * 28;
    // 672 octet tasks: r = c*8+p (x row / k-octet), gy = patch col.
    for (int t = tid; t < 672; t += 256) {
      const int r  = t / 28;            // 0..23  (k bytes [8r, 8r+8))
      const int gy = t - r * 28;        // 0..27
      const int c = r >> 3, p = r & 7;
      const float4* src =
          (const float4*)(x + (size_t)((b * 3 + c) * 224 + gx * 8 + p) * 224);
      float4 a0 = src[gy * 2], a1 = src[gy * 2 + 1];
      uint2 q;
      q.x = q4i8(a0, inv);
      q.y = q4i8(a1, inv);
      stg8[gy][r] = q;
    }
    __syncthreads();
    // contiguous stream-out: rows m = b*784+gx*28 + [0,28), 28*12 uint4
    uint4* dst = Aq + (size_t)(b * 784 + gx * 28) * 12;
    for (int t = tid; t < 336; t += 256) {
      const int gy = t / 12;
      const int j  = t - gy * 12;
      uint2 lo = stg8[gy][2 * j], hi = stg8[gy][2 * j + 1];
      uint4 v; v.x = lo.x; v.y = lo.y; v.z = hi.x; v.w = hi.y;
      dst[t] = v;
    }
  } else {
    const float inv = 1.0f / sw;
    const int g = (blockIdx.x - NAXB) * 256 + tid;   // < 9,216
    float4 a0 = w4[g * 4], a1 = w4[g * 4 + 1];
    float4 a2 = w4[g * 4 + 2], a3 = w4[g * 4 + 3];
    uint4 q;
    q.x = q4i8(a0, inv); q.y = q4i8(a1, inv);
    q.z = q4i8(a2, inv); q.w = q4i8(a3, inv);
    Wq[g] = q;                                       // flat order == [d][k]
  }
}

// ---------------------------------------------------------------------------
// Pure int8 code-GEMM, mfma_i32_16x16x64_i8 (K=192 = 3 steps).
//   A frag: A[m = lane&15][k = (lane>>4)*16 + j] -> uint4 @ m*12 + lq + ks*4
//   B frag: W[n = lane&15][k = (lane>>4)*16 + j] -> uint4 @ n*12 + lq + ks*4
//   D:      row = (lane>>4)*4 + reg, col = lane&15
// Epilogue: i32->f32 + per-wave LDS transpose -> NON-TEMPORAL f32x4 stores
// (out is never re-read; keep the 154MB stream from evicting Aq in L2).
// ---------------------------------------------------------------------------
__global__ __launch_bounds__(256) void gemm_k(
    const uint4* __restrict__ Aq, const uint4* __restrict__ Wq,
    const float* __restrict__ bias, const float* __restrict__ slots,
    float* __restrict__ out) {
  __shared__ float tr[4 * 1280];       // per wave: 64 cols x 20 (16 rows+pad)
  const int tid  = threadIdx.x;
  const int lane = tid & 63;
  const int wid  = tid >> 6;
  const int wm   = wid >> 1;   // 0..1
  const int wn   = wid & 1;    // 0..1
  const int lm   = lane & 15;
  const int lq   = lane >> 4;  // 0..3
  const int m0   = blockIdx.x * 128;   // 392 m-tiles (392%8==0 -> XCD-local)
  const int n0   = blockIdx.y * 128;   // 6 n-tiles

  int abase[4], bbase[4];
#pragma unroll
  for (int tm = 0; tm < 4; ++tm)
    abase[tm] = (m0 + wm * 64 + tm * 16 + lm) * 12 + lq;
#pragma unroll
  for (int tn = 0; tn < 4; ++tn)
    bbase[tn] = (n0 + wn * 64 + tn * 16 + lm) * 12 + lq;

  i32x4 acc[4][4] = {};

#pragma unroll
  for (int ks = 0; ks < 3; ++ks) {     // K=64 per step
    i32x4 af[4], bf[4];
#pragma unroll
    for (int tm = 0; tm < 4; ++tm)
      af[tm] = __builtin_bit_cast(i32x4, Aq[abase[tm] + ks * 4]);
#pragma unroll
    for (int tn = 0; tn < 4; ++tn)
      bf[tn] = __builtin_bit_cast(i32x4, Wq[bbase[tn] + ks * 4]);
#pragma unroll
    for (int tm = 0; tm < 4; ++tm)
#pragma unroll
      for (int tn = 0; tn < 4; ++tn)
        acc[tm][tn] = __builtin_amdgcn_mfma_i32_16x16x64_i8(
            af[tm], bf[tn], acc[tm][tn], 0, 0, 0);
  }

  // ---- epilogue: i32->f32, wave-local transpose, nt f32x4 stores ----
  const float scale = slots[0] * slots[1];
  float* T = &tr[wid * 1280];
  const int c4 = lane & 15;                       // float4-column group
  const int gc = n0 + wn * 64 + c4 * 4;
  const float4 bv = *(const float4*)&bias[gc];    // hoisted: c4 fixed per lane

#pragma unroll
  for (int tm = 0; tm < 4; ++tm) {
#pragma unroll
    for (int tn = 0; tn < 4; ++tn) { // element (row=lq*4+j, col=tn*16+lm)
      f32x4 f;
#pragma unroll
      for (int j = 0; j < 4; ++j) f[j] = (float)acc[tm][tn][j];
      *(f32x4*)&T[(tn * 16 + lm) * 20 + lq * 4] = f;
    }
    asm volatile("s_waitcnt lgkmcnt(0)" ::: "memory");
#pragma unroll
    for (int i = 0; i < 4; ++i) {
      const int s = (lane >> 4) + i * 4;          // row 0..15 of this stripe
      f32x4 o;
      o[0] = fmaf(T[(c4 * 4 + 0) * 20 + s], scale, bv.x);
      o[1] = fmaf(T[(c4 * 4 + 1) * 20 + s], scale, bv.y);
      o[2] = fmaf(T[(c4 * 4 + 2) * 20 + s], scale, bv.z);
      o[3] = fmaf(T[(c4 * 4 + 3) * 20 + s], scale, bv.w);
      const int gm = m0 + wm * 64 + tm * 16 + s;
      __builtin_nontemporal_store(o, (f32x4*)&out[(size_t)gm * 768 + gc]);
    }
    asm volatile("s_waitcnt lgkmcnt(0)" ::: "memory");  // drain reads before next tm rewrites T
  }
}

// ---------------------------------------------------------------------------

extern "C" void kernel_launch(void* const* d_in, const int* in_sizes, int n_in,
                              void* d_out, int out_size, void* d_ws, size_t ws_size,
                              hipStream_t stream) {
  const float* xf = (const float*)d_in[0];       // 9,633,792 fp32
  const float4* w4 = (const float4*)d_in[1];     //   147,456 fp32
  const float* bias = (const float*)d_in[2];     //       768 fp32
  float* out = (float*)d_out;                    // 38,535,168 fp32

  char* ws = (char*)d_ws;
  float* slots    = (float*)ws;                  // [0]=s_x, [1]=s_w
  float* partials = (float*)(ws + 256);          // 1828 floats
  uint4* Wq       = (uint4*)(ws + 8192);         //   147,456 B int8 codes
  uint4* Aq       = (uint4*)(ws + 8192 + 147456);// 9,633,792 B int8 codes

  absmax_k<<<NAXB + NAWB, 256, 0, stream>>>(xf, w4, partials);
  quant_xw_k<<<NAXB + NAWB, 256, 0, stream>>>(xf, w4, Aq, Wq, partials, slots);
  gemm_k<<<dim3(392, 6), 256, 0, stream>>>(Aq, Wq, bias, slots, out);
}

// Round 6
// 199.792 us; speedup vs baseline: 2.1028x; 1.0409x over previous
//
#include <hip/hip_runtime.h>
#include <stdint.h>

// ---------------------------------------------------------------------------
// PatchEmbed + HMQConv2d fake-quant, fp32 I/O.
//   s_x = max(max|x|,1e-8)/127 ; s_w = max(max|w|,1e-8)/127
//   out[b, gx*28+gy, d] = (sum_k qx*qw) * s_x*s_w + bias[d]
// GEMM M=50176, N=768, K=192, int8 codes, mfma_i32_16x16x64_i8 (exact:
// |acc| <= 192*127^2 << 2^31).
//
// Round-10: EXACT REVERT to the round-7 configuration (measured 200.3us,
// the best of the session). Post-mortems of every structural variant:
//  - R4 fuse quant into GEMM: VALU-bound, worse.
//  - R8 device-wide spin barrier: +250us idle (cross-XCD coherence on one
//    hot line serializes; never hand-roll device barriers on MI355X).
//  - R9a absmax retiled to quant's (b,gx) tiles: XCD L2 capacity fails
//    (4.8MB slice > 4MB L2) -> thrash, and the gather pattern is worse
//    than pure grid-stride for a BW-bound pass.
//  - R9b nontemporal out stores: bypasses L2 write-combining, worse.
// Chain = absmax (grid-stride, ~6.5us) + quant (LDS-transpose, ~8us) +
// gemm (24 dwordx4 loads + 48 MFMA/wave, ~28us) ~= 45us vs ~38us traffic
// floor; remaining ~155us of the timed quantum is harness re-poison fills
// (602MB @ ~6.6TB/s each) outside kernel control.
// ---------------------------------------------------------------------------

using f32x4 = __attribute__((ext_vector_type(4))) float;
using i32x4 = __attribute__((ext_vector_type(4))) int;

static __device__ __forceinline__ uint32_t q4i8(float4 v, float inv_s) {
  // 4 floats -> 4 int8 codes packed LE (byte 0 = v.x)
  int q0 = (int)rintf(fminf(fmaxf(v.x * inv_s, -127.0f), 127.0f));
  int q1 = (int)rintf(fminf(fmaxf(v.y * inv_s, -127.0f), 127.0f));
  int q2 = (int)rintf(fminf(fmaxf(v.z * inv_s, -127.0f), 127.0f));
  int q3 = (int)rintf(fminf(fmaxf(v.w * inv_s, -127.0f), 127.0f));
  return (uint32_t)(q0 & 0xff) | ((uint32_t)(q1 & 0xff) << 8) |
         ((uint32_t)(q2 & 0xff) << 16) | ((uint32_t)(q3 & 0xff) << 24);
}

// ---- absmax: blocks [0,1024) cover x, [1024,1088) cover w -----------------
#define NBX 1024
#define NBW 64
__global__ void absmax_k(const float4* __restrict__ x, int nx4,
                         const float4* __restrict__ w, int nw4,
                         float* __restrict__ partials) {
  __shared__ float red[4];
  float m = 0.0f;
  if (blockIdx.x < NBX) {
    for (int i = blockIdx.x * 256 + threadIdx.x; i < nx4; i += NBX * 256) {
      float4 u = x[i];
      m = fmaxf(m, fabsf(u.x)); m = fmaxf(m, fabsf(u.y));
      m = fmaxf(m, fabsf(u.z)); m = fmaxf(m, fabsf(u.w));
    }
  } else {
    for (int i = (blockIdx.x - NBX) * 256 + threadIdx.x; i < nw4; i += NBW * 256) {
      float4 u = w[i];
      m = fmaxf(m, fabsf(u.x)); m = fmaxf(m, fabsf(u.y));
      m = fmaxf(m, fabsf(u.z)); m = fmaxf(m, fabsf(u.w));
    }
  }
#pragma unroll
  for (int off = 32; off > 0; off >>= 1) m = fmaxf(m, __shfl_down(m, off, 64));
  if ((threadIdx.x & 63) == 0) red[threadIdx.x >> 6] = m;
  __syncthreads();
  if (threadIdx.x == 0) {
    m = fmaxf(fmaxf(red[0], red[1]), fmaxf(red[2], red[3]));
    partials[blockIdx.x] = m;
  }
}

// ---- quant both ------------------------------------------------------------
// x blocks [0,1792): block = (b,gx). Stage 28 Aq rows (m = b*784+gx*28+gy,
// 192 int8 each) through LDS: x reads coalesced (consecutive gy = consecutive
// 32B of an x row), Aq written as one contiguous 5376B stream per block.
// w blocks [1792,1828): 16 floats/thread -> uint4 int8 stores, flat [d][k].
// Prologue (all blocks): reduce absmax partials -> s_x, s_w in-registers
// (1088 floats, L2-hot, ~free); block 0 publishes slots for the gemm.
#define NQXB 1792
#define NQWB 36
__global__ __launch_bounds__(256) void quant_xw_k(
    const float* __restrict__ x, const float4* __restrict__ w4,
    uint4* __restrict__ Aq, uint4* __restrict__ Wq,
    const float* __restrict__ partials, float* __restrict__ slots) {
  __shared__ float redx[4];
  __shared__ float redw_s;
  __shared__ uint2 stg8[28][26];   // [gy][octet], row padded 24->26 uint2
  const int tid = threadIdx.x;

  // ---- scales (every block) ----
  float mx = 0.0f;
  for (int i = tid; i < NBX; i += 256) mx = fmaxf(mx, partials[i]);
#pragma unroll
  for (int off = 32; off > 0; off >>= 1) mx = fmaxf(mx, __shfl_down(mx, off, 64));
  if ((tid & 63) == 0) redx[tid >> 6] = mx;
  if (tid < 64) {
    float mw = partials[NBX + tid];
#pragma unroll
    for (int off = 32; off > 0; off >>= 1) mw = fmaxf(mw, __shfl_down(mw, off, 64));
    if (tid == 0) redw_s = mw;
  }
  __syncthreads();
  float sx = fmaxf(fmaxf(redx[0], redx[1]), fmaxf(redx[2], redx[3]));
  sx = fmaxf(sx, 1e-8f) * (1.0f / 127.0f);
  float sw = fmaxf(redw_s, 1e-8f) * (1.0f / 127.0f);
  if (blockIdx.x == 0 && tid == 0) { slots[0] = sx; slots[1] = sw; }

  if (blockIdx.x < NQXB) {
    const float inv = 1.0f / sx;
    const int b  = blockIdx.x / 28;
    const int gx = blockIdx.x - b * 28;
    // 672 octet tasks: r = c*8+p (x row / k-octet), gy = patch col.
    for (int t = tid; t < 672; t += 256) {
      const int r  = t / 28;            // 0..23  (k bytes [8r, 8r+8))
      const int gy = t - r * 28;        // 0..27
      const int c = r >> 3, p = r & 7;
      const float4* src =
          (const float4*)(x + (size_t)((b * 3 + c) * 224 + gx * 8 + p) * 224);
      float4 a0 = src[gy * 2], a1 = src[gy * 2 + 1];
      uint2 q;
      q.x = q4i8(a0, inv);
      q.y = q4i8(a1, inv);
      stg8[gy][r] = q;
    }
    __syncthreads();
    // contiguous stream-out: rows m = b*784+gx*28 + [0,28), 28*12 uint4
    uint4* dst = Aq + (size_t)(b * 784 + gx * 28) * 12;
    for (int t = tid; t < 336; t += 256) {
      const int gy = t / 12;
      const int j  = t - gy * 12;
      uint2 lo = stg8[gy][2 * j], hi = stg8[gy][2 * j + 1];
      uint4 v; v.x = lo.x; v.y = lo.y; v.z = hi.x; v.w = hi.y;
      dst[t] = v;
    }
  } else {
    const float inv = 1.0f / sw;
    const int g = (blockIdx.x - NQXB) * 256 + tid;   // < 9,216
    float4 a0 = w4[g * 4], a1 = w4[g * 4 + 1];
    float4 a2 = w4[g * 4 + 2], a3 = w4[g * 4 + 3];
    uint4 q;
    q.x = q4i8(a0, inv); q.y = q4i8(a1, inv);
    q.z = q4i8(a2, inv); q.w = q4i8(a3, inv);
    Wq[g] = q;                                       // flat order == [d][k]
  }
}

// ---------------------------------------------------------------------------
// Pure int8 code-GEMM, mfma_i32_16x16x64_i8 (K=192 = 3 steps).
//   A frag: A[m = lane&15][k = (lane>>4)*16 + j] -> uint4 @ m*12 + lq + ks*4
//   B frag: W[n = lane&15][k = (lane>>4)*16 + j] -> uint4 @ n*12 + lq + ks*4
//   D:      row = (lane>>4)*4 + reg, col = lane&15
// Epilogue: i32->f32 convert + per-wave LDS transpose -> float4 stores.
// ---------------------------------------------------------------------------
__global__ __launch_bounds__(256) void gemm_k(
    const uint4* __restrict__ Aq, const uint4* __restrict__ Wq,
    const float* __restrict__ bias, const float* __restrict__ slots,
    float* __restrict__ out) {
  __shared__ float tr[4 * 1280];       // per wave: 64 cols x 20 (16 rows+pad)
  const int tid  = threadIdx.x;
  const int lane = tid & 63;
  const int wid  = tid >> 6;
  const int wm   = wid >> 1;   // 0..1
  const int wn   = wid & 1;    // 0..1
  const int lm   = lane & 15;
  const int lq   = lane >> 4;  // 0..3
  const int m0   = blockIdx.x * 128;   // 392 m-tiles (392%8==0 -> XCD-local)
  const int n0   = blockIdx.y * 128;   // 6 n-tiles

  int abase[4], bbase[4];
#pragma unroll
  for (int tm = 0; tm < 4; ++tm)
    abase[tm] = (m0 + wm * 64 + tm * 16 + lm) * 12 + lq;
#pragma unroll
  for (int tn = 0; tn < 4; ++tn)
    bbase[tn] = (n0 + wn * 64 + tn * 16 + lm) * 12 + lq;

  i32x4 acc[4][4] = {};

#pragma unroll
  for (int ks = 0; ks < 3; ++ks) {     // K=64 per step
    i32x4 af[4], bf[4];
#pragma unroll
    for (int tm = 0; tm < 4; ++tm)
      af[tm] = __builtin_bit_cast(i32x4, Aq[abase[tm] + ks * 4]);
#pragma unroll
    for (int tn = 0; tn < 4; ++tn)
      bf[tn] = __builtin_bit_cast(i32x4, Wq[bbase[tn] + ks * 4]);
#pragma unroll
    for (int tm = 0; tm < 4; ++tm)
#pragma unroll
      for (int tn = 0; tn < 4; ++tn)
        acc[tm][tn] = __builtin_amdgcn_mfma_i32_16x16x64_i8(
            af[tm], bf[tn], acc[tm][tn], 0, 0, 0);
  }

  // ---- epilogue: i32->f32, wave-local transpose, float4 stores ----
  const float scale = slots[0] * slots[1];
  float* T = &tr[wid * 1280];
  const int c4 = lane & 15;                       // float4-column group
  const int gc = n0 + wn * 64 + c4 * 4;
  const float4 bv = *(const float4*)&bias[gc];    // hoisted: c4 fixed per lane

#pragma unroll
  for (int tm = 0; tm < 4; ++tm) {
#pragma unroll
    for (int tn = 0; tn < 4; ++tn) { // element (row=lq*4+j, col=tn*16+lm)
      f32x4 f;
#pragma unroll
      for (int j = 0; j < 4; ++j) f[j] = (float)acc[tm][tn][j];
      *(f32x4*)&T[(tn * 16 + lm) * 20 + lq * 4] = f;
    }
    asm volatile("s_waitcnt lgkmcnt(0)" ::: "memory");
#pragma unroll
    for (int i = 0; i < 4; ++i) {
      const int s = (lane >> 4) + i * 4;          // row 0..15 of this stripe
      float4 v;
      v.x = T[(c4 * 4 + 0) * 20 + s];
      v.y = T[(c4 * 4 + 1) * 20 + s];
      v.z = T[(c4 * 4 + 2) * 20 + s];
      v.w = T[(c4 * 4 + 3) * 20 + s];
      float4 o;
      o.x = fmaf(v.x, scale, bv.x);
      o.y = fmaf(v.y, scale, bv.y);
      o.z = fmaf(v.z, scale, bv.z);
      o.w = fmaf(v.w, scale, bv.w);
      const int gm = m0 + wm * 64 + tm * 16 + s;
      *(float4*)&out[(size_t)gm * 768 + gc] = o;
    }
    asm volatile("s_waitcnt lgkmcnt(0)" ::: "memory");  // drain reads before next tm rewrites T
  }
}

// ---------------------------------------------------------------------------

extern "C" void kernel_launch(void* const* d_in, const int* in_sizes, int n_in,
                              void* d_out, int out_size, void* d_ws, size_t ws_size,
                              hipStream_t stream) {
  const float* xf = (const float*)d_in[0];       // 9,633,792 fp32
  const float4* x4 = (const float4*)d_in[0];
  const float4* w4 = (const float4*)d_in[1];     //   147,456 fp32
  const float* bias = (const float*)d_in[2];     //       768 fp32
  float* out = (float*)d_out;                    // 38,535,168 fp32

  char* ws = (char*)d_ws;
  float* slots    = (float*)ws;                  // [0]=s_x, [1]=s_w
  float* partials = (float*)(ws + 256);          // 1088 floats
  uint4* Wq       = (uint4*)(ws + 8192);         //   147,456 B int8 codes
  uint4* Aq       = (uint4*)(ws + 8192 + 147456);// 9,633,792 B int8 codes

  const int nx4 = 9633792 / 4;   // 2,408,448
  const int nw4 = 147456 / 4;    //    36,864

  absmax_k<<<NBX + NBW, 256, 0, stream>>>(x4, nx4, w4, nw4, partials);
  quant_xw_k<<<NQXB + NQWB, 256, 0, stream>>>(xf, w4, Aq, Wq, partials, slots);
  gemm_k<<<dim3(392, 6), 256, 0, stream>>>(Aq, Wq, bias, slots, out);
}